// Round 1
// baseline (1304.906 us; speedup 1.0000x reference)
//
#include <hip/hip_runtime.h>
#include <math.h>

// StickBreakingVAE forward: B=32768, D=784, H=500, K=50
//   h     = relu(x @ enc_w1 + enc_b1)            [B,H]
//   alpha = softplus(h @ w_alpha + b_alpha)      [B,K]
//   beta  = softplus(h @ w_beta  + b_beta)       [B,K]
//   v     = (1 - u^(1/beta))^(1/alpha)
//   pi    = stick-breaking(v)                    [B,K]
//   hd    = relu(pi @ dec_w1 + dec_b1)           [B,H]
//   recon = sigmoid(hd @ dec_w2 + dec_b2)        [B,D]
// out = [recon | alpha | beta] flat f32.

#define TILE 64
#define BKK 16

// ACT: 0 = relu, 1 = softplus, 2 = sigmoid
template<int ACT>
__global__ __launch_bounds__(256) void gemm_bias_act(
    const float* __restrict__ A, const float* __restrict__ Bm,
    const float* __restrict__ bias, float* __restrict__ C,
    int M, int N, int K)
{
    __shared__ float As[BKK][TILE];   // [k][m]
    __shared__ float Bs[BKK][TILE];   // [k][n]

    const int tid = threadIdx.x;
    const int tx = tid & 15;          // n-group (4 cols each)
    const int ty = tid >> 4;          // m-group (4 rows each)
    const int block_m = blockIdx.y * TILE;
    const int block_n = blockIdx.x * TILE;

    float acc[4][4] = {};

    for (int k0 = 0; k0 < K; k0 += BKK) {
        // load A tile 64(m) x 16(k); M always divisible by 64 here
        #pragma unroll
        for (int i = 0; i < 4; ++i) {
            int e = tid + i * 256;
            int m = e >> 4;
            int kk = e & 15;
            int gk = k0 + kk;
            As[kk][m] = (gk < K) ? A[(long)(block_m + m) * K + gk] : 0.0f;
        }
        // load B tile 16(k) x 64(n)
        #pragma unroll
        for (int i = 0; i < 4; ++i) {
            int e = tid + i * 256;
            int kk = e >> 6;
            int n = e & 63;
            int gk = k0 + kk;
            int gn = block_n + n;
            Bs[kk][n] = (gk < K && gn < N) ? Bm[(long)gk * N + gn] : 0.0f;
        }
        __syncthreads();
        #pragma unroll
        for (int kk = 0; kk < BKK; ++kk) {
            float ra[4], rb[4];
            #pragma unroll
            for (int i = 0; i < 4; ++i) ra[i] = As[kk][ty * 4 + i];
            #pragma unroll
            for (int j = 0; j < 4; ++j) rb[j] = Bs[kk][tx * 4 + j];
            #pragma unroll
            for (int i = 0; i < 4; ++i)
                #pragma unroll
                for (int j = 0; j < 4; ++j)
                    acc[i][j] = fmaf(ra[i], rb[j], acc[i][j]);
        }
        __syncthreads();
    }

    #pragma unroll
    for (int i = 0; i < 4; ++i) {
        int gm = block_m + ty * 4 + i;
        #pragma unroll
        for (int j = 0; j < 4; ++j) {
            int gn = block_n + tx * 4 + j;
            if (gn < N) {
                float z = acc[i][j] + bias[gn];
                if (ACT == 0) {
                    z = fmaxf(z, 0.0f);
                } else if (ACT == 1) {
                    // stable softplus = logaddexp(z, 0)
                    z = (z > 0.0f) ? z + log1pf(expf(-z)) : log1pf(expf(z));
                } else {
                    z = (z >= 0.0f) ? 1.0f / (1.0f + expf(-z))
                                    : expf(z) / (1.0f + expf(z));
                }
                C[(long)gm * N + gn] = z;
            }
        }
    }
}

// Kumaraswamy inverse-CDF sample + stick-breaking (sequential over K per row)
__global__ __launch_bounds__(256) void sample_pi(
    const float* __restrict__ u,
    const float* __restrict__ alpha,
    const float* __restrict__ beta,
    float* __restrict__ pi, int B, int K)
{
    int r = blockIdx.x * blockDim.x + threadIdx.x;
    if (r >= B) return;
    float run = 1.0f;
    for (int k = 0; k < K; ++k) {
        long idx = (long)r * K + k;
        float a = alpha[idx];
        float b = beta[idx];
        float uu = u[idx];
        float t = powf(uu, 1.0f / b);            // u^(1/beta)
        float v = powf(1.0f - t, 1.0f / a);      // (1-t)^(1/alpha)
        pi[idx] = v * run;
        run *= (1.0f - v);
    }
}

extern "C" void kernel_launch(void* const* d_in, const int* in_sizes, int n_in,
                              void* d_out, int out_size, void* d_ws, size_t ws_size,
                              hipStream_t stream) {
    const float* x       = (const float*)d_in[0];
    const float* u       = (const float*)d_in[1];
    const float* enc_w1  = (const float*)d_in[2];
    const float* enc_b1  = (const float*)d_in[3];
    const float* w_alpha = (const float*)d_in[4];
    const float* b_alpha = (const float*)d_in[5];
    const float* w_beta  = (const float*)d_in[6];
    const float* b_beta  = (const float*)d_in[7];
    const float* dec_w1  = (const float*)d_in[8];
    const float* dec_b1  = (const float*)d_in[9];
    const float* dec_w2  = (const float*)d_in[10];
    const float* dec_b2  = (const float*)d_in[11];

    const int B = 32768, D = 784, H = 500, K = 50;

    float* out   = (float*)d_out;
    float* recon = out;                          // B*D
    float* alpha = out + (size_t)B * D;          // B*K
    float* beta  = alpha + (size_t)B * K;        // B*K

    float* h  = (float*)d_ws;                    // B*H floats
    float* pi = h + (size_t)B * H;               // B*K floats
    float* hd = h;                               // reuse h region (h dead after alpha/beta)

    dim3 blk(256);

    // h = relu(x @ enc_w1 + enc_b1)   [32768,784]@[784,500]
    gemm_bias_act<0><<<dim3((H + TILE - 1) / TILE, B / TILE), blk, 0, stream>>>(
        x, enc_w1, enc_b1, h, B, H, D);
    // alpha = softplus(h @ w_alpha + b_alpha)   [32768,500]@[500,50]
    gemm_bias_act<1><<<dim3((K + TILE - 1) / TILE, B / TILE), blk, 0, stream>>>(
        h, w_alpha, b_alpha, alpha, B, K, H);
    // beta = softplus(h @ w_beta + b_beta)
    gemm_bias_act<1><<<dim3((K + TILE - 1) / TILE, B / TILE), blk, 0, stream>>>(
        h, w_beta, b_beta, beta, B, K, H);
    // v + stick-breaking -> pi
    sample_pi<<<dim3(B / 256), blk, 0, stream>>>(u, alpha, beta, pi, B, K);
    // hd = relu(pi @ dec_w1 + dec_b1)   [32768,50]@[50,500]
    gemm_bias_act<0><<<dim3((H + TILE - 1) / TILE, B / TILE), blk, 0, stream>>>(
        pi, dec_w1, dec_b1, hd, B, H, K);
    // recon = sigmoid(hd @ dec_w2 + dec_b2)   [32768,500]@[500,784]
    gemm_bias_act<2><<<dim3((D + TILE - 1) / TILE, B / TILE), blk, 0, stream>>>(
        hd, dec_w2, dec_b2, recon, B, D, H);
}

// Round 2
// 349.129 us; speedup vs baseline: 3.7376x; 3.7376x over previous
//
#include <hip/hip_runtime.h>
#include <math.h>

// StickBreakingVAE forward, bf16-MFMA pipeline. B=32768, D=784, H=500, K=50.
// GEMM1: h   = relu(x @ enc_w1 + b)        M=32768 K=784->800 N=500->512 (bf16 out)
// GEMM2/3:  [alpha|beta] = softplus(h @ [w_a|w_b] + b)  K=512 N=100->128 (f32 out)
// sample_pi: v/stick-breaking -> pib bf16 [B,64]
// GEMM4: hd  = relu(pi @ dec_w1 + b)       K=50->64  N=500->512 (bf16 out)
// GEMM5: rec = sigmoid(hd @ dec_w2 + b)    K=500->512 N=784->896 (f32 masked out)

typedef __bf16 bf16x8 __attribute__((ext_vector_type(8)));
typedef float f32x4 __attribute__((ext_vector_type(4)));

#define BATCH 32768
#define BM 128
#define BN 128
#define BK 32

__device__ __forceinline__ unsigned short bf16_bits(float f) {
    __bf16 b = (__bf16)f;
    return __builtin_bit_cast(unsigned short, b);
}

// MODE 0: relu -> bf16 C [ldc padded, full tile stored]
// MODE 1: softplus -> alpha (gn<50) / beta (50<=gn<100) f32 compact [B,50] each
// MODE 2: sigmoid -> f32 C [B, Nreal], store only gn < Nreal
template<int MODE, bool AF32>
__global__ __launch_bounds__(256) void mfma_gemm(
    const void* __restrict__ Av, const unsigned short* __restrict__ Bt,
    const float* __restrict__ bias, void* __restrict__ Cv,
    int Kpad, int Kreal, int lda, int ldc, int Nreal)
{
    __shared__ unsigned short As[BM * BK];   // [row][32k], 16B-granule XOR swizzled
    __shared__ unsigned short Bs[BN * BK];

    const int tid = threadIdx.x;
    const int l = tid & 63;
    const int wid = tid >> 6;
    const int wr = wid >> 1, wc = wid & 1;
    const long block_m = (long)blockIdx.y * BM;
    const int block_n = blockIdx.x * BN;

    f32x4 acc[4][4] = {};

    for (int k0 = 0; k0 < Kpad; k0 += BK) {
        // ---- stage A tile (128 rows x 32 k) ----
        #pragma unroll
        for (int i = 0; i < 2; ++i) {
            int gid = tid + i * 256;          // 512 granules of 16B
            int r = gid >> 2;
            int kg = gid & 3;
            int gk = k0 + kg * 8;
            uint4 v;
            if (AF32) {
                const float* Af = (const float*)Av;
                union { __bf16 b[8]; uint4 u; } pk;
                if (gk < Kreal) {
                    const float4* p = (const float4*)(Af + (block_m + r) * (size_t)lda + gk);
                    float4 f0 = p[0];
                    float4 f1 = p[1];
                    pk.b[0] = (__bf16)f0.x; pk.b[1] = (__bf16)f0.y;
                    pk.b[2] = (__bf16)f0.z; pk.b[3] = (__bf16)f0.w;
                    pk.b[4] = (__bf16)f1.x; pk.b[5] = (__bf16)f1.y;
                    pk.b[6] = (__bf16)f1.z; pk.b[7] = (__bf16)f1.w;
                } else {
                    pk.u = make_uint4(0, 0, 0, 0);
                }
                v = pk.u;
            } else {
                const unsigned short* Ab = (const unsigned short*)Av;
                v = *(const uint4*)(Ab + (block_m + r) * (size_t)lda + gk);
            }
            *(uint4*)((char*)As + r * 64 + ((kg ^ (r & 3)) * 16)) = v;
        }
        // ---- stage B tile (128 n-rows x 32 k), Bt is [Npad][Kpad] bf16 ----
        #pragma unroll
        for (int i = 0; i < 2; ++i) {
            int gid = tid + i * 256;
            int r = gid >> 2;
            int kg = gid & 3;
            int gk = k0 + kg * 8;
            uint4 v = *(const uint4*)(Bt + (size_t)(block_n + r) * Kpad + gk);
            *(uint4*)((char*)Bs + r * 64 + ((kg ^ (r & 3)) * 16)) = v;
        }
        __syncthreads();

        // ---- fragments + MFMA ----
        bf16x8 af[4], bfr[4];
        const int kg = l >> 4;
        #pragma unroll
        for (int mi = 0; mi < 4; ++mi) {
            int row = wr * 64 + mi * 16 + (l & 15);
            af[mi] = *(const bf16x8*)((const char*)As + row * 64 + ((kg ^ (row & 3)) * 16));
        }
        #pragma unroll
        for (int ni = 0; ni < 4; ++ni) {
            int row = wc * 64 + ni * 16 + (l & 15);
            bfr[ni] = *(const bf16x8*)((const char*)Bs + row * 64 + ((kg ^ (row & 3)) * 16));
        }
        #pragma unroll
        for (int mi = 0; mi < 4; ++mi)
            #pragma unroll
            for (int ni = 0; ni < 4; ++ni)
                acc[mi][ni] = __builtin_amdgcn_mfma_f32_16x16x32_bf16(
                    af[mi], bfr[ni], acc[mi][ni], 0, 0, 0);
        __syncthreads();
    }

    // ---- epilogue: C/D layout col=lane&15, row=(lane>>4)*4+j ----
    const int cf = l & 15;
    const int rg = (l >> 4) * 4;
    #pragma unroll
    for (int mi = 0; mi < 4; ++mi) {
        #pragma unroll
        for (int ni = 0; ni < 4; ++ni) {
            int gn = block_n + wc * 64 + ni * 16 + cf;
            float bs = bias[gn];
            #pragma unroll
            for (int j = 0; j < 4; ++j) {
                long gm = block_m + wr * 64 + mi * 16 + rg + j;
                float z = acc[mi][ni][j] + bs;
                if (MODE == 0) {
                    z = fmaxf(z, 0.f);
                    ((unsigned short*)Cv)[gm * ldc + gn] = bf16_bits(z);
                } else if (MODE == 1) {
                    z = (z > 0.f) ? z + log1pf(expf(-z)) : log1pf(expf(z));
                    float* out = (float*)Cv;
                    if (gn < 50)       out[gm * 50 + gn] = z;
                    else if (gn < 100) out[(size_t)BATCH * 50 + gm * 50 + (gn - 50)] = z;
                } else {
                    if (gn < Nreal) {
                        z = (z >= 0.f) ? 1.f / (1.f + expf(-z))
                                       : expf(z) / (1.f + expf(z));
                        ((float*)Cv)[gm * Nreal + gn] = z;
                    }
                }
            }
        }
    }
}

// transpose + cast + pad a weight [Kr][Nr] f32 -> [Npad][Kpad] bf16, plus padded bias
__global__ __launch_bounds__(256) void prep_bt(
    const float* __restrict__ W, const float* __restrict__ bias,
    unsigned short* __restrict__ Bt, float* __restrict__ bpad,
    int Kr, int Nr, int Kpad, int Npad)
{
    int idx = blockIdx.x * 256 + threadIdx.x;
    if (idx >= Npad * Kpad) return;
    int n = idx / Kpad, k = idx - n * Kpad;
    float v = (n < Nr && k < Kr) ? W[(size_t)k * Nr + n] : 0.f;
    Bt[idx] = bf16_bits(v);
    if (k == 0) bpad[n] = (n < Nr) ? bias[n] : 0.f;
}

// concat [w_alpha | w_beta] -> [128][512] bf16 (transposed), bias likewise
__global__ __launch_bounds__(256) void prep_wab(
    const float* __restrict__ Wa, const float* __restrict__ Wb,
    const float* __restrict__ ba, const float* __restrict__ bb,
    unsigned short* __restrict__ Bt, float* __restrict__ bpad)
{
    int idx = blockIdx.x * 256 + threadIdx.x;
    if (idx >= 128 * 512) return;
    int n = idx >> 9, k = idx & 511;
    float v = 0.f;
    if (k < 500) {
        if (n < 50)       v = Wa[(size_t)k * 50 + n];
        else if (n < 100) v = Wb[(size_t)k * 50 + (n - 50)];
    }
    Bt[idx] = bf16_bits(v);
    if (k == 0) bpad[n] = (n < 50) ? ba[n] : ((n < 100) ? bb[n - 50] : 0.f);
}

// Kumaraswamy sample + stick-breaking -> pib bf16 [B][64] (padded)
__global__ __launch_bounds__(256) void sample_pi(
    const float* __restrict__ u, const float* __restrict__ alpha,
    const float* __restrict__ beta, unsigned short* __restrict__ pib)
{
    int r = blockIdx.x * 256 + threadIdx.x;
    if (r >= BATCH) return;
    float run = 1.f;
    #pragma unroll 1
    for (int k = 0; k < 50; ++k) {
        size_t idx = (size_t)r * 50 + k;
        float a = alpha[idx], b = beta[idx], uu = u[idx];
        float t = powf(uu, 1.f / b);
        float v = powf(1.f - t, 1.f / a);
        pib[(size_t)r * 64 + k] = bf16_bits(v * run);
        run *= (1.f - v);
    }
    #pragma unroll
    for (int k = 50; k < 64; ++k) pib[(size_t)r * 64 + k] = 0;
}

extern "C" void kernel_launch(void* const* d_in, const int* in_sizes, int n_in,
                              void* d_out, int out_size, void* d_ws, size_t ws_size,
                              hipStream_t stream) {
    const float* x       = (const float*)d_in[0];
    const float* u       = (const float*)d_in[1];
    const float* enc_w1  = (const float*)d_in[2];
    const float* enc_b1  = (const float*)d_in[3];
    const float* w_alpha = (const float*)d_in[4];
    const float* b_alpha = (const float*)d_in[5];
    const float* w_beta  = (const float*)d_in[6];
    const float* b_beta  = (const float*)d_in[7];
    const float* dec_w1  = (const float*)d_in[8];
    const float* dec_b1  = (const float*)d_in[9];
    const float* dec_w2  = (const float*)d_in[10];
    const float* dec_b2  = (const float*)d_in[11];

    const int D = 784, H = 500;

    float* out   = (float*)d_out;
    float* recon = out;
    float* alpha = out + (size_t)BATCH * D;   // [B,50]; beta follows at +B*50

    // workspace layout (bytes)
    char* ws = (char*)d_ws;
    unsigned short* w1b  = (unsigned short*)(ws);                 // 512*800*2   = 819200
    unsigned short* wab  = (unsigned short*)(ws + 819200);        // 128*512*2   = 131072
    unsigned short* dw1b = (unsigned short*)(ws + 950272);        // 512*64*2    = 65536
    unsigned short* dw2b = (unsigned short*)(ws + 1015808);       // 896*512*2   = 917504
    float* bias1  = (float*)(ws + 1933312);                       // 512*4
    float* biasab = (float*)(ws + 1935360);                       // 128*4
    float* biasd1 = (float*)(ws + 1935872);                       // 512*4
    float* biasd2 = (float*)(ws + 1937920);                       // 896*4
    unsigned short* h    = (unsigned short*)(ws + 2097152);       // 32768*512*2 = 33554432
    unsigned short* pib  = (unsigned short*)(ws + 2097152);       // reuse h region after GEMM2/3
    unsigned short* hdb  = (unsigned short*)(ws + 35651584);      // 32768*512*2
    // peak usage ~69.2 MB

    // ---- prep weights ----
    prep_bt<<<dim3((512 * 800 + 255) / 256), 256, 0, stream>>>(
        enc_w1, enc_b1, w1b, bias1, 784, 500, 800, 512);
    prep_wab<<<dim3(256), 256, 0, stream>>>(w_alpha, w_beta, b_alpha, b_beta, wab, biasab);
    prep_bt<<<dim3((512 * 64 + 255) / 256), 256, 0, stream>>>(
        dec_w1, dec_b1, dw1b, biasd1, 50, 500, 64, 512);
    prep_bt<<<dim3((896 * 512 + 255) / 256), 256, 0, stream>>>(
        dec_w2, dec_b2, dw2b, biasd2, 500, 784, 512, 896);

    // ---- GEMM1: h = relu(x @ enc_w1 + b1), A f32 on-the-fly cast ----
    mfma_gemm<0, true><<<dim3(512 / BN, BATCH / BM), 256, 0, stream>>>(
        x, w1b, bias1, h, 800, 784, 784, 512, 500);

    // ---- GEMM2/3 fused: [alpha|beta] = softplus(h @ wab + b) ----
    mfma_gemm<1, false><<<dim3(1, BATCH / BM), 256, 0, stream>>>(
        h, wab, biasab, alpha, 512, 512, 512, 0, 100);

    // ---- sample: pi (bf16, padded to 64) ----
    sample_pi<<<dim3(BATCH / 256), 256, 0, stream>>>(u, alpha, alpha + (size_t)BATCH * 50, pib);

    // ---- GEMM4: hd = relu(pi @ dec_w1 + b) ----
    mfma_gemm<0, false><<<dim3(512 / BN, BATCH / BM), 256, 0, stream>>>(
        pib, dw1b, biasd1, hdb, 64, 64, 64, 512, 500);

    // ---- GEMM5: recon = sigmoid(hd @ dec_w2 + b) ----
    mfma_gemm<2, false><<<dim3(896 / BN, BATCH / BM), 256, 0, stream>>>(
        hdb, dw2b, biasd2, recon, 512, 512, 512, 784, 784);
}

// Round 3
// 251.628 us; speedup vs baseline: 5.1858x; 1.3875x over previous
//
#include <hip/hip_runtime.h>
#include <math.h>

// StickBreakingVAE forward, bf16-MFMA + global_load_lds pipeline.
// B=32768, D=784, H=500, K=50.
// cast_x: x f32 [B,784] -> xb bf16 [B,832]   (xb lives in d_out recon scratch)
// GEMM1: h   = relu(xb @ enc_w1 + b)     K=832 N=512  (bf16, ws)
// GEMM2/3:   [alpha|beta] = softplus(h @ wab + b)  K=512 N=128 (f32 -> d_out)
// sample_pi: stick-breaking -> pib bf16 [B,64] (ws)
// GEMM4: hd  = relu(pib @ dec_w1 + b)    K=64  N=512  (bf16, reuses h region)
// GEMM5: rec = sigmoid(hd @ dec_w2 + b)  K=512 N=896  (f32 masked -> d_out, over xb)

typedef __bf16 bf16x8 __attribute__((ext_vector_type(8)));
typedef float f32x4 __attribute__((ext_vector_type(4)));

#define BATCH 32768
#define BM 128
#define BN 128
#define BK 64

__device__ __forceinline__ unsigned short bf16_bits(float f) {
    __bf16 b = (__bf16)f;
    return __builtin_bit_cast(unsigned short, b);
}

__device__ __forceinline__ void gll16(const unsigned short* src, unsigned short* ldsdst) {
    __builtin_amdgcn_global_load_lds(
        (const __attribute__((address_space(1))) unsigned int*)src,
        (__attribute__((address_space(3))) unsigned int*)ldsdst,
        16, 0, 0);
}

// MODE 0: relu -> bf16 C [ldc], full padded tile stored
// MODE 1: softplus -> alpha (gn<50) / beta (50<=gn<100) f32 compact [B,50] each
// MODE 2: sigmoid -> f32 C [B,Nreal], store only gn < Nreal
template<int MODE>
__global__ __launch_bounds__(256) void mfma_gemm(
    const unsigned short* __restrict__ A,   // [M][lda] bf16 (zero-padded)
    const unsigned short* __restrict__ Bt,  // [Npad][Kpad] bf16 (zero-padded)
    const float* __restrict__ bias,         // [Npad]
    void* __restrict__ Cv,
    int Kpad, int lda, int ldc, int Nreal)
{
    __shared__ unsigned short As[BM * BK];   // linear: row*64 + granule*8 (granule=16B)
    __shared__ unsigned short Bs[BN * BK];

    const int tid = threadIdx.x;
    const int l = tid & 63;
    const int wid = tid >> 6;
    const int wr = wid >> 1, wc = wid & 1;
    const size_t block_m = (size_t)blockIdx.y * BM;
    const int block_n = blockIdx.x * BN;

    const int lr = l & 15;   // fragment row-in-16
    const int kh = l >> 4;   // fragment k-granule (0..3)

    f32x4 acc[4][4] = {};

    for (int k0 = 0; k0 < Kpad; k0 += BK) {
        // stage A,B: linear LDS dest (wave-uniform base + lane*16),
        // global source granule XOR-swizzled so swizzled ds_read is conflict-free
        #pragma unroll
        for (int i = 0; i < 4; ++i) {
            int chunk = wid * 4 + i;          // 16 chunks of 1KB each
            int gid = chunk * 64 + l;         // granule id 0..1023
            int r = gid >> 3;                 // tile row 0..127
            int kgs = (gid & 7) ^ (r & 7);    // swizzled source granule
            gll16(A + (block_m + r) * (size_t)lda + k0 + kgs * 8, As + chunk * 512);
            gll16(Bt + (size_t)(block_n + r) * Kpad + k0 + kgs * 8, Bs + chunk * 512);
        }
        __syncthreads();

        #pragma unroll
        for (int s = 0; s < 2; ++s) {
            bf16x8 af[4], bf[4];
            #pragma unroll
            for (int mi = 0; mi < 4; ++mi) {
                int row = wr * 64 + mi * 16 + lr;
                int g = (s * 4 + kh) ^ (row & 7);
                af[mi] = *(const bf16x8*)(As + row * 64 + g * 8);
            }
            #pragma unroll
            for (int ni = 0; ni < 4; ++ni) {
                int row = wc * 64 + ni * 16 + lr;
                int g = (s * 4 + kh) ^ (row & 7);
                bf[ni] = *(const bf16x8*)(Bs + row * 64 + g * 8);
            }
            #pragma unroll
            for (int mi = 0; mi < 4; ++mi)
                #pragma unroll
                for (int ni = 0; ni < 4; ++ni)
                    acc[mi][ni] = __builtin_amdgcn_mfma_f32_16x16x32_bf16(
                        af[mi], bf[ni], acc[mi][ni], 0, 0, 0);
        }
        __syncthreads();
    }

    // epilogue: C/D layout col=lane&15, row=(lane>>4)*4+j (verified r2)
    const int rg = (l >> 4) * 4;
    #pragma unroll
    for (int mi = 0; mi < 4; ++mi) {
        #pragma unroll
        for (int ni = 0; ni < 4; ++ni) {
            int gn = block_n + wc * 64 + ni * 16 + lr;
            float bs = bias[gn];
            #pragma unroll
            for (int j = 0; j < 4; ++j) {
                long gm = block_m + wr * 64 + mi * 16 + rg + j;
                float z = acc[mi][ni][j] + bs;
                if (MODE == 0) {
                    z = fmaxf(z, 0.f);
                    ((unsigned short*)Cv)[gm * ldc + gn] = bf16_bits(z);
                } else if (MODE == 1) {
                    z = (z > 0.f) ? z + __logf(1.f + __expf(-z))
                                  : __logf(1.f + __expf(z));
                    float* out = (float*)Cv;
                    if (gn < 50)       out[gm * 50 + gn] = z;
                    else if (gn < 100) out[(size_t)BATCH * 50 + gm * 50 + (gn - 50)] = z;
                } else {
                    if (gn < Nreal) {
                        z = (z >= 0.f) ? 1.f / (1.f + __expf(-z))
                                       : __expf(z) / (1.f + __expf(z));
                        ((float*)Cv)[gm * Nreal + gn] = z;
                    }
                }
            }
        }
    }
}

// x f32 [B][784] -> xb bf16 [B][832] zero-padded
__global__ __launch_bounds__(256) void cast_x(
    const float* __restrict__ x, unsigned short* __restrict__ xb)
{
    int gid = blockIdx.x * 256 + threadIdx.x;   // granule of 8 elems; B*104 total
    int r = gid / 104;
    int c = gid - r * 104;
    union { __bf16 b[8]; uint4 u; } pk;
    if (c < 98) {
        const float4* p = (const float4*)(x + (size_t)r * 784 + c * 8);
        float4 f0 = p[0], f1 = p[1];
        pk.b[0] = (__bf16)f0.x; pk.b[1] = (__bf16)f0.y;
        pk.b[2] = (__bf16)f0.z; pk.b[3] = (__bf16)f0.w;
        pk.b[4] = (__bf16)f1.x; pk.b[5] = (__bf16)f1.y;
        pk.b[6] = (__bf16)f1.z; pk.b[7] = (__bf16)f1.w;
    } else {
        pk.u = make_uint4(0, 0, 0, 0);
    }
    *(uint4*)(xb + (size_t)r * 832 + c * 8) = pk.u;
}

// weight [Kr][Nr] f32 -> [Npad][Kpad] bf16 transposed, bias padded
__global__ __launch_bounds__(256) void prep_bt(
    const float* __restrict__ W, const float* __restrict__ bias,
    unsigned short* __restrict__ Bt, float* __restrict__ bpad,
    int Kr, int Nr, int Kpad, int Npad)
{
    int idx = blockIdx.x * 256 + threadIdx.x;
    if (idx >= Npad * Kpad) return;
    int n = idx / Kpad, k = idx - n * Kpad;
    float v = (n < Nr && k < Kr) ? W[(size_t)k * Nr + n] : 0.f;
    Bt[idx] = bf16_bits(v);
    if (k == 0) bpad[n] = (n < Nr) ? bias[n] : 0.f;
}

// [w_alpha | w_beta] -> [128][512] bf16 transposed
__global__ __launch_bounds__(256) void prep_wab(
    const float* __restrict__ Wa, const float* __restrict__ Wb,
    const float* __restrict__ ba, const float* __restrict__ bb,
    unsigned short* __restrict__ Bt, float* __restrict__ bpad)
{
    int idx = blockIdx.x * 256 + threadIdx.x;
    if (idx >= 128 * 512) return;
    int n = idx >> 9, k = idx & 511;
    float v = 0.f;
    if (k < 500) {
        if (n < 50)       v = Wa[(size_t)k * 50 + n];
        else if (n < 100) v = Wb[(size_t)k * 50 + (n - 50)];
    }
    Bt[idx] = bf16_bits(v);
    if (k == 0) bpad[n] = (n < 50) ? ba[n] : ((n < 100) ? bb[n - 50] : 0.f);
}

// Kumaraswamy sample + stick-breaking -> pib bf16 [B][64]
__global__ __launch_bounds__(256) void sample_pi(
    const float* __restrict__ u, const float* __restrict__ alpha,
    const float* __restrict__ beta, unsigned short* __restrict__ pib)
{
    int r = blockIdx.x * 256 + threadIdx.x;
    if (r >= BATCH) return;
    float run = 1.f;
    #pragma unroll 1
    for (int k = 0; k < 50; ++k) {
        size_t idx = (size_t)r * 50 + k;
        float a = alpha[idx], b = beta[idx], uu = u[idx];
        float t = exp2f(__fdividef(log2f(uu), b));          // u^(1/beta)
        float v = exp2f(__fdividef(log2f(1.f - t), a));     // (1-t)^(1/alpha)
        pib[(size_t)r * 64 + k] = bf16_bits(v * run);
        run *= (1.f - v);
    }
    #pragma unroll
    for (int k = 50; k < 64; ++k) pib[(size_t)r * 64 + k] = 0;
}

extern "C" void kernel_launch(void* const* d_in, const int* in_sizes, int n_in,
                              void* d_out, int out_size, void* d_ws, size_t ws_size,
                              hipStream_t stream) {
    const float* x       = (const float*)d_in[0];
    const float* u       = (const float*)d_in[1];
    const float* enc_w1  = (const float*)d_in[2];
    const float* enc_b1  = (const float*)d_in[3];
    const float* w_alpha = (const float*)d_in[4];
    const float* b_alpha = (const float*)d_in[5];
    const float* w_beta  = (const float*)d_in[6];
    const float* b_beta  = (const float*)d_in[7];
    const float* dec_w1  = (const float*)d_in[8];
    const float* dec_b1  = (const float*)d_in[9];
    const float* dec_w2  = (const float*)d_in[10];
    const float* dec_b2  = (const float*)d_in[11];

    const int D = 784;

    float* out   = (float*)d_out;
    float* recon = out;                              // [B,784] f32
    float* alpha = out + (size_t)BATCH * D;          // [B,50]
    // beta follows alpha at +B*50 (written by MODE 1 epilogue)

    // xb scratch lives in the recon region (dead until GEMM5): 54.5MB < 102.8MB
    unsigned short* xb = (unsigned short*)d_out;     // [B][832] bf16

    // workspace layout
    char* ws = (char*)d_ws;
    unsigned short* w1b  = (unsigned short*)(ws);             // 512*832*2 = 851968
    unsigned short* wab  = (unsigned short*)(ws + 851968);    // 128*512*2 = 131072
    unsigned short* dw1b = (unsigned short*)(ws + 983040);    // 512*64*2  = 65536
    unsigned short* dw2b = (unsigned short*)(ws + 1048576);   // 896*512*2 = 917504
    float* bias1  = (float*)(ws + 1966080);
    float* biasab = (float*)(ws + 1968128);
    float* biasd1 = (float*)(ws + 1970688);
    float* biasd2 = (float*)(ws + 1972736);
    unsigned short* h    = (unsigned short*)(ws + 2097152);   // [B][512] bf16 = 33.5MB
    unsigned short* pib  = (unsigned short*)(ws + 35651584);  // [B][64]  bf16 = 4.2MB
    unsigned short* hdb  = h;                                  // reuse h (dead after GEMM2/3)
    // peak ws = 39.85 MB

    // ---- prep ----
    cast_x<<<dim3(BATCH * 104 / 256), 256, 0, stream>>>(x, xb);
    prep_bt<<<dim3(512 * 832 / 256), 256, 0, stream>>>(
        enc_w1, enc_b1, w1b, bias1, 784, 500, 832, 512);
    prep_wab<<<dim3(256), 256, 0, stream>>>(w_alpha, w_beta, b_alpha, b_beta, wab, biasab);
    prep_bt<<<dim3(512 * 64 / 256), 256, 0, stream>>>(
        dec_w1, dec_b1, dw1b, biasd1, 50, 500, 64, 512);
    prep_bt<<<dim3(896 * 512 / 256), 256, 0, stream>>>(
        dec_w2, dec_b2, dw2b, biasd2, 500, 784, 512, 896);

    // ---- GEMM1: h = relu(xb @ enc_w1 + b1) ----
    mfma_gemm<0><<<dim3(512 / BN, BATCH / BM), 256, 0, stream>>>(
        xb, w1b, bias1, h, 832, 832, 512, 500);

    // ---- GEMM2/3: [alpha|beta] = softplus(h @ wab + b) ----
    mfma_gemm<1><<<dim3(1, BATCH / BM), 256, 0, stream>>>(
        h, wab, biasab, alpha, 512, 512, 0, 100);

    // ---- sample ----
    sample_pi<<<dim3(BATCH / 256), 256, 0, stream>>>(
        u, alpha, alpha + (size_t)BATCH * 50, pib);

    // ---- GEMM4: hd = relu(pib @ dec_w1 + b) ----
    mfma_gemm<0><<<dim3(512 / BN, BATCH / BM), 256, 0, stream>>>(
        pib, dw1b, biasd1, hdb, 64, 64, 512, 500);

    // ---- GEMM5: recon = sigmoid(hd @ dec_w2 + b) (overwrites xb) ----
    mfma_gemm<2><<<dim3(896 / BN, BATCH / BM), 256, 0, stream>>>(
        hdb, dw2b, biasd2, recon, 512, 512, 784, 784);
}

// Round 4
// 175.454 us; speedup vs baseline: 7.4373x; 1.4342x over previous
//
#include <hip/hip_runtime.h>
#include <math.h>

// StickBreakingVAE forward, bf16-MFMA + global_load_lds pipeline + XCD swizzle.
// B=32768, D=784, H=500, K=50.
// cast_x: x f32 [B,784] -> xb bf16 [B,832]   (xb lives in d_out recon scratch)
// GEMM1: h   = relu(xb @ enc_w1 + b)     K=832 N=512  (bf16, ws)
// GEMM2/3:   [alpha|beta] = softplus(h @ wab + b)  K=512 N=128 (f32 -> d_out)
// sample_pi: wave-per-row stick-breaking scan -> pib bf16 [B,64] (ws)
// GEMM4: hd  = relu(pib @ dec_w1 + b)    K=64  N=512  (bf16, reuses h region)
// GEMM5: rec = sigmoid(hd @ dec_w2 + b)  K=512 N=896  (f32 masked -> d_out, over xb)

typedef __bf16 bf16x8 __attribute__((ext_vector_type(8)));
typedef float f32x4 __attribute__((ext_vector_type(4)));

#define BATCH 32768
#define BM 128
#define BN 128
#define BK 64

__device__ __forceinline__ unsigned short bf16_bits(float f) {
    __bf16 b = (__bf16)f;
    return __builtin_bit_cast(unsigned short, b);
}

__device__ __forceinline__ void gll16(const unsigned short* src, unsigned short* ldsdst) {
    __builtin_amdgcn_global_load_lds(
        (const __attribute__((address_space(1))) unsigned int*)src,
        (__attribute__((address_space(3))) unsigned int*)ldsdst,
        16, 0, 0);
}

// MODE 0: relu -> bf16 C [ldc], full padded tile stored
// MODE 1: softplus -> alpha (gn<50) / beta (50<=gn<100) f32 compact [B,50] each
// MODE 2: sigmoid -> f32 C [B,Nreal], store only gn < Nreal
template<int MODE>
__global__ __launch_bounds__(256) void mfma_gemm(
    const unsigned short* __restrict__ A,   // [M][lda] bf16 (zero-padded)
    const unsigned short* __restrict__ Bt,  // [Npad][Kpad] bf16 (zero-padded)
    const float* __restrict__ bias,         // [Npad]
    void* __restrict__ Cv,
    int Kpad, int lda, int ldc, int Nreal, int nbx)
{
    __shared__ unsigned short As[BM * BK];   // linear: row*64 + granule*8 (granule=16B)
    __shared__ unsigned short Bs[BN * BK];

    // ---- chunked bijective XCD swizzle (T1, m204): same-A-panel blocks -> same XCD L2
    const int nwg = gridDim.x;
    const int orig = blockIdx.x;
    const int q = nwg >> 3, r8 = nwg & 7;
    const int xcd = orig & 7;
    const int chunkbase = (xcd < r8) ? xcd * (q + 1) : r8 * (q + 1) + (xcd - r8) * q;
    const int wgid = chunkbase + (orig >> 3);
    const int bn = wgid % nbx;               // n fastest within chunk -> A-panel reuse
    const size_t block_m = (size_t)(wgid / nbx) * BM;
    const int block_n = bn * BN;

    const int tid = threadIdx.x;
    const int l = tid & 63;
    const int wid = tid >> 6;
    const int wr = wid >> 1, wc = wid & 1;

    const int lr = l & 15;   // fragment row-in-16
    const int kh = l >> 4;   // fragment k-granule (0..3)

    f32x4 acc[4][4] = {};

    for (int k0 = 0; k0 < Kpad; k0 += BK) {
        // stage A,B: linear LDS dest (wave-uniform base + lane*16),
        // global source granule XOR-swizzled so swizzled ds_read is conflict-free
        #pragma unroll
        for (int i = 0; i < 4; ++i) {
            int chunk = wid * 4 + i;          // 16 chunks of 1KB each
            int gid = chunk * 64 + l;         // granule id 0..1023
            int r = gid >> 3;                 // tile row 0..127
            int kgs = (gid & 7) ^ (r & 7);    // swizzled source granule
            gll16(A + (block_m + r) * (size_t)lda + k0 + kgs * 8, As + chunk * 512);
            gll16(Bt + (size_t)(block_n + r) * Kpad + k0 + kgs * 8, Bs + chunk * 512);
        }
        __syncthreads();

        #pragma unroll
        for (int s = 0; s < 2; ++s) {
            bf16x8 af[4], bf[4];
            #pragma unroll
            for (int mi = 0; mi < 4; ++mi) {
                int row = wr * 64 + mi * 16 + lr;
                int g = (s * 4 + kh) ^ (row & 7);
                af[mi] = *(const bf16x8*)(As + row * 64 + g * 8);
            }
            #pragma unroll
            for (int ni = 0; ni < 4; ++ni) {
                int row = wc * 64 + ni * 16 + lr;
                int g = (s * 4 + kh) ^ (row & 7);
                bf[ni] = *(const bf16x8*)(Bs + row * 64 + g * 8);
            }
            #pragma unroll
            for (int mi = 0; mi < 4; ++mi)
                #pragma unroll
                for (int ni = 0; ni < 4; ++ni)
                    acc[mi][ni] = __builtin_amdgcn_mfma_f32_16x16x32_bf16(
                        af[mi], bf[ni], acc[mi][ni], 0, 0, 0);
        }
        __syncthreads();
    }

    // epilogue: C/D layout col=lane&15, row=(lane>>4)*4+j
    const int rg = (l >> 4) * 4;
    #pragma unroll
    for (int mi = 0; mi < 4; ++mi) {
        #pragma unroll
        for (int ni = 0; ni < 4; ++ni) {
            int gn = block_n + wc * 64 + ni * 16 + lr;
            float bs = bias[gn];
            #pragma unroll
            for (int j = 0; j < 4; ++j) {
                long gm = block_m + wr * 64 + mi * 16 + rg + j;
                float z = acc[mi][ni][j] + bs;
                if (MODE == 0) {
                    z = fmaxf(z, 0.f);
                    ((unsigned short*)Cv)[gm * ldc + gn] = bf16_bits(z);
                } else if (MODE == 1) {
                    z = (z > 0.f) ? z + __logf(1.f + __expf(-z))
                                  : __logf(1.f + __expf(z));
                    float* out = (float*)Cv;
                    if (gn < 50)       out[gm * 50 + gn] = z;
                    else if (gn < 100) out[(size_t)BATCH * 50 + gm * 50 + (gn - 50)] = z;
                } else {
                    if (gn < Nreal) {
                        z = (z >= 0.f) ? 1.f / (1.f + __expf(-z))
                                       : __expf(z) / (1.f + __expf(z));
                        ((float*)Cv)[gm * Nreal + gn] = z;
                    }
                }
            }
        }
    }
}

// x f32 [B][784] -> xb bf16 [B][832] zero-padded
__global__ __launch_bounds__(256) void cast_x(
    const float* __restrict__ x, unsigned short* __restrict__ xb)
{
    int gid = blockIdx.x * 256 + threadIdx.x;   // granule of 8 elems; B*104 total
    int r = gid / 104;
    int c = gid - r * 104;
    union { __bf16 b[8]; uint4 u; } pk;
    if (c < 98) {
        const float4* p = (const float4*)(x + (size_t)r * 784 + c * 8);
        float4 f0 = p[0], f1 = p[1];
        pk.b[0] = (__bf16)f0.x; pk.b[1] = (__bf16)f0.y;
        pk.b[2] = (__bf16)f0.z; pk.b[3] = (__bf16)f0.w;
        pk.b[4] = (__bf16)f1.x; pk.b[5] = (__bf16)f1.y;
        pk.b[6] = (__bf16)f1.z; pk.b[7] = (__bf16)f1.w;
    } else {
        pk.u = make_uint4(0, 0, 0, 0);
    }
    *(uint4*)(xb + (size_t)r * 832 + c * 8) = pk.u;
}

// weight [Kr][Nr] f32 -> [Npad][Kpad] bf16 transposed, bias padded
__global__ __launch_bounds__(256) void prep_bt(
    const float* __restrict__ W, const float* __restrict__ bias,
    unsigned short* __restrict__ Bt, float* __restrict__ bpad,
    int Kr, int Nr, int Kpad, int Npad)
{
    int idx = blockIdx.x * 256 + threadIdx.x;
    if (idx >= Npad * Kpad) return;
    int n = idx / Kpad, k = idx - n * Kpad;
    float v = (n < Nr && k < Kr) ? W[(size_t)k * Nr + n] : 0.f;
    Bt[idx] = bf16_bits(v);
    if (k == 0) bpad[n] = (n < Nr) ? bias[n] : 0.f;
}

// [w_alpha | w_beta] -> [128][512] bf16 transposed
__global__ __launch_bounds__(256) void prep_wab(
    const float* __restrict__ Wa, const float* __restrict__ Wb,
    const float* __restrict__ ba, const float* __restrict__ bb,
    unsigned short* __restrict__ Bt, float* __restrict__ bpad)
{
    int idx = blockIdx.x * 256 + threadIdx.x;
    if (idx >= 128 * 512) return;
    int n = idx >> 9, k = idx & 511;
    float v = 0.f;
    if (k < 500) {
        if (n < 50)       v = Wa[(size_t)k * 50 + n];
        else if (n < 100) v = Wb[(size_t)k * 50 + (n - 50)];
    }
    Bt[idx] = bf16_bits(v);
    if (k == 0) bpad[n] = (n < 50) ? ba[n] : ((n < 100) ? bb[n - 50] : 0.f);
}

// Kumaraswamy sample + stick-breaking. One WAVE per row: lane k computes v_k,
// then 6-step shuffle prefix-product scan replaces the serial cumprod.
__global__ __launch_bounds__(256) void sample_pi(
    const float* __restrict__ u, const float* __restrict__ alpha,
    const float* __restrict__ beta, unsigned short* __restrict__ pib)
{
    int row = (blockIdx.x * 256 + threadIdx.x) >> 6;   // wave index = row
    int lane = threadIdx.x & 63;
    size_t base = (size_t)row * 50;

    float v = 0.f, w = 1.f;
    if (lane < 50) {
        float a = alpha[base + lane];
        float b = beta[base + lane];
        float uu = u[base + lane];
        float t = exp2f(__fdividef(log2f(uu), b));          // u^(1/beta)
        v = exp2f(__fdividef(log2f(1.f - t), a));           // (1-t)^(1/alpha)
        w = 1.f - v;
    }
    // inclusive prefix product of w across the wave
    float p = w;
    #pragma unroll
    for (int off = 1; off < 64; off <<= 1) {
        float t = __shfl_up(p, off, 64);
        if (lane >= off) p *= t;
    }
    // exclusive scan -> pi = v * prod_{j<k}(1-v_j)
    float ex = __shfl_up(p, 1, 64);
    if (lane == 0) ex = 1.f;
    float pi = v * ex;
    pib[(size_t)row * 64 + lane] = (lane < 50) ? bf16_bits(pi) : (unsigned short)0;
}

extern "C" void kernel_launch(void* const* d_in, const int* in_sizes, int n_in,
                              void* d_out, int out_size, void* d_ws, size_t ws_size,
                              hipStream_t stream) {
    const float* x       = (const float*)d_in[0];
    const float* u       = (const float*)d_in[1];
    const float* enc_w1  = (const float*)d_in[2];
    const float* enc_b1  = (const float*)d_in[3];
    const float* w_alpha = (const float*)d_in[4];
    const float* b_alpha = (const float*)d_in[5];
    const float* w_beta  = (const float*)d_in[6];
    const float* b_beta  = (const float*)d_in[7];
    const float* dec_w1  = (const float*)d_in[8];
    const float* dec_b1  = (const float*)d_in[9];
    const float* dec_w2  = (const float*)d_in[10];
    const float* dec_b2  = (const float*)d_in[11];

    const int D = 784;

    float* out   = (float*)d_out;
    float* recon = out;                              // [B,784] f32
    float* alpha = out + (size_t)BATCH * D;          // [B,50]; beta at +B*50

    // xb scratch lives in the recon region (dead until GEMM5)
    unsigned short* xb = (unsigned short*)d_out;     // [B][832] bf16

    // workspace layout
    char* ws = (char*)d_ws;
    unsigned short* w1b  = (unsigned short*)(ws);             // 512*832*2 = 851968
    unsigned short* wab  = (unsigned short*)(ws + 851968);    // 128*512*2 = 131072
    unsigned short* dw1b = (unsigned short*)(ws + 983040);    // 512*64*2  = 65536
    unsigned short* dw2b = (unsigned short*)(ws + 1048576);   // 896*512*2 = 917504
    float* bias1  = (float*)(ws + 1966080);
    float* biasab = (float*)(ws + 1968128);
    float* biasd1 = (float*)(ws + 1970688);
    float* biasd2 = (float*)(ws + 1972736);
    unsigned short* h    = (unsigned short*)(ws + 2097152);   // [B][512] bf16 = 33.5MB
    unsigned short* pib  = (unsigned short*)(ws + 35651584);  // [B][64]  bf16 = 4.2MB
    unsigned short* hdb  = h;                                  // reuse h (dead after GEMM2/3)
    // peak ws = 39.85 MB

    // ---- prep ----
    cast_x<<<dim3(BATCH * 104 / 256), 256, 0, stream>>>(x, xb);
    prep_bt<<<dim3(512 * 832 / 256), 256, 0, stream>>>(
        enc_w1, enc_b1, w1b, bias1, 784, 500, 832, 512);
    prep_wab<<<dim3(256), 256, 0, stream>>>(w_alpha, w_beta, b_alpha, b_beta, wab, biasab);
    prep_bt<<<dim3(512 * 64 / 256), 256, 0, stream>>>(
        dec_w1, dec_b1, dw1b, biasd1, 50, 500, 64, 512);
    prep_bt<<<dim3(896 * 512 / 256), 256, 0, stream>>>(
        dec_w2, dec_b2, dw2b, biasd2, 500, 784, 512, 896);

    // ---- GEMM1: h = relu(xb @ enc_w1 + b1), grid 4n x 256m -> 1024 ----
    mfma_gemm<0><<<dim3((512 / BN) * (BATCH / BM)), 256, 0, stream>>>(
        xb, w1b, bias1, h, 832, 832, 512, 500, 512 / BN);

    // ---- GEMM2/3: [alpha|beta] = softplus(h @ wab + b), grid 256 ----
    mfma_gemm<1><<<dim3(BATCH / BM), 256, 0, stream>>>(
        h, wab, biasab, alpha, 512, 512, 0, 100, 1);

    // ---- sample: one wave per row ----
    sample_pi<<<dim3(BATCH * 64 / 256), 256, 0, stream>>>(
        u, alpha, alpha + (size_t)BATCH * 50, pib);

    // ---- GEMM4: hd = relu(pib @ dec_w1 + b) ----
    mfma_gemm<0><<<dim3((512 / BN) * (BATCH / BM)), 256, 0, stream>>>(
        pib, dw1b, biasd1, hdb, 64, 64, 512, 500, 512 / BN);

    // ---- GEMM5: recon = sigmoid(hd @ dec_w2 + b) (overwrites xb) ----
    mfma_gemm<2><<<dim3((896 / BN) * (BATCH / BM)), 256, 0, stream>>>(
        hdb, dw2b, biasd2, recon, 512, 512, 784, 784, 896 / BN);
}